// Round 1
// baseline (1265.398 us; speedup 1.0000x reference)
//
#include <hip/hip_runtime.h>
#include <math.h>

#define HH 128
#define WW 128
#define CC 64
#define OHH 256
#define OWW 256
#define NB 2

__device__ __forceinline__ float gelu_f(float x){
    return 0.5f * x * (1.0f + erff(x * 0.70710678118654752440f));
}

// ---------------------------------------------------------------------------
// prep_kernel: one block, 256 threads.
//   Stage 1: m_emb[p][o] for the 4 output-pixel parities p=(oy&1)*2+(ox&1)
//            (scale=2 => du,dv in {+0.25,-0.25} by parity only).
//   Stage 2: contrib[p][oo] = bk1[oo] + sum_j wk1[oo][576+j] * m_emb[p][j]
// ---------------------------------------------------------------------------
__global__ __launch_bounds__(256) void prep_kernel(
    const float* __restrict__ w1m, const float* __restrict__ b1m,
    const float* __restrict__ w2m, const float* __restrict__ b2m,
    const float* __restrict__ wk1, const float* __restrict__ bk1,
    float* __restrict__ contrib)
{
    __shared__ float m_emb[4][64];
    const int t = threadIdx.x;
    const int p = t >> 6;
    const int o = t & 63;

    const float du = (p & 1) ? -0.25f : 0.25f;   // ox even -> +0.25
    const float dv = (p >> 1) ? -0.25f : 0.25f;  // oy even -> +0.25
    const float mv[5] = {2.0f, du, dv, 0.5f, 0.3f};

    float enc[85];
    #pragma unroll
    for (int f = 0; f < 5; ++f){
        enc[f*17] = mv[f];
        float fr = 3.14159265358979323846f;
        #pragma unroll
        for (int b = 0; b < 8; ++b){
            float xb = mv[f] * fr;
            enc[f*17 + 1 + b] = sinf(xb);
            enc[f*17 + 9 + b] = cosf(xb);
            fr *= 2.0f;
        }
    }

    // m_emb[p][o] = b2m[o] + sum_j gelu(w1m[j]·enc + b1m[j]) * w2m[o][j]
    float acc = b2m[o];
    for (int j = 0; j < 64; ++j){
        float h = b1m[j];
        #pragma unroll
        for (int i = 0; i < 85; ++i) h += enc[i] * w1m[j*85 + i];
        acc += gelu_f(h) * w2m[o*64 + j];
    }
    m_emb[p][o] = acc;
    __syncthreads();

    for (int e = t; e < 512; e += 256){
        const int pp = e >> 7;
        const int oo = e & 127;
        float a = bk1[oo];
        #pragma unroll
        for (int j = 0; j < 64; ++j) a += m_emb[pp][j] * wk1[oo*640 + 576 + j];
        contrib[e] = a;
    }
}

// ---------------------------------------------------------------------------
// main_kernel: 1 thread = 1 output pixel. 512 blocks x 256 threads.
// ---------------------------------------------------------------------------
__global__ __launch_bounds__(256) void main_kernel(
    const float* __restrict__ feat,
    const float* __restrict__ wk1,                                  // 128x640
    const float* __restrict__ wk2, const float* __restrict__ bk2,   // 9x128, 9
    const float* __restrict__ wr1, const float* __restrict__ br1,   // 64x64, 64
    const float* __restrict__ wr2, const float* __restrict__ br2,   // 3x64, 3
    const float* __restrict__ contrib,                              // 4x128
    float* __restrict__ out)
{
    const int tid = blockIdx.x * 256 + threadIdx.x;
    const int b  = tid >> 16;
    const int qi = tid & 65535;
    const int oy = qi >> 8;
    const int ox = qi & 255;

    // cell = floor((o+0.5)/2 - 0.5) = (o-1)>>1 (arithmetic shift)
    const int cell_y = (oy - 1) >> 1;
    const int cell_x = (ox - 1) >> 1;
    const int cy = cell_y < 0 ? 0 : cell_y;
    const int cx = cell_x < 0 ? 0 : cell_x;

    int ry[3], rx[3];
    #pragma unroll
    for (int k = 0; k < 3; ++k){
        int r = cy - 1 + k;
        ry[k] = (r < 0) ? -r : ((r >= HH) ? 2*HH - 2 - r : r);
        int c = cx - 1 + k;
        rx[k] = (c < 0) ? -c : ((c >= WW) ? 2*WW - 2 - c : c);
    }

    const int p = ((oy & 1) << 1) | (ox & 1);
    const float* __restrict__ fb = feat + (size_t)b * CC * HH * WW;

    // ---- weight-MLP layer 1 (patch part) + layer 2, o-chunks of 32 ----
    float w9[9];
    #pragma unroll
    for (int k = 0; k < 9; ++k) w9[k] = bk2[k];

    for (int oc = 0; oc < 4; ++oc){
        float acc[32];
        #pragma unroll
        for (int j = 0; j < 32; ++j) acc[j] = contrib[p*128 + oc*32 + j];

        for (int c = 0; c < CC; ++c){
            const float* __restrict__ fc = fb + c * (HH*WW);
            float v[9];
            #pragma unroll
            for (int ky = 0; ky < 3; ++ky){
                const float* __restrict__ frow = fc + ry[ky] * WW;
                #pragma unroll
                for (int kx = 0; kx < 3; ++kx) v[ky*3 + kx] = frow[rx[kx]];
            }
            const float* __restrict__ wrow0 = wk1 + (oc*32) * 640 + c * 9;
            #pragma unroll
            for (int j = 0; j < 32; ++j){
                const float* __restrict__ wrow = wrow0 + j * 640;
                float a = acc[j];
                #pragma unroll
                for (int kk = 0; kk < 9; ++kk) a += v[kk] * wrow[kk];
                acc[j] = a;
            }
        }
        #pragma unroll
        for (int j = 0; j < 32; ++j){
            const float h = gelu_f(acc[j]);
            const int o = oc*32 + j;
            #pragma unroll
            for (int k = 0; k < 9; ++k) w9[k] += h * wk2[k*128 + o];
        }
    }

    // ---- softmax over 9 ----
    float mx = w9[0];
    #pragma unroll
    for (int k = 1; k < 9; ++k) mx = fmaxf(mx, w9[k]);
    float sum = 0.0f;
    #pragma unroll
    for (int k = 0; k < 9; ++k){ w9[k] = expf(w9[k] - mx); sum += w9[k]; }
    const float inv = 1.0f / sum;
    #pragma unroll
    for (int k = 0; k < 9; ++k) w9[k] *= inv;

    // ---- f_q[c] = sum_k w9[k] * flat[k*64+c], flat[j] = feat(ch=j/9, kk=j%9) ----
    float fq[64];
    #pragma unroll
    for (int c = 0; c < 64; ++c){
        float a = 0.0f;
        #pragma unroll
        for (int k = 0; k < 9; ++k){
            const int j  = k*64 + c;
            const int ch = j / 9;      // compile-time after unroll
            const int kk = j % 9;
            a += w9[k] * fb[ch*(HH*WW) + ry[kk/3]*WW + rx[kk%3]];
        }
        fq[c] = a;
    }

    // ---- RGB MLP: 64 -> 64 (gelu) -> 3 ----
    float r0 = br2[0], r1 = br2[1], r2 = br2[2];
    for (int o = 0; o < 64; ++o){
        float a = br1[o];
        #pragma unroll
        for (int c = 0; c < 64; ++c) a += fq[c] * wr1[o*64 + c];
        const float h = gelu_f(a);
        r0 += h * wr2[o];
        r1 += h * wr2[64 + o];
        r2 += h * wr2[128 + o];
    }

    const int pix = (oy << 8) | ox;
    out[((size_t)(b*3 + 0) << 16) + pix] = r0;
    out[((size_t)(b*3 + 1) << 16) + pix] = r1;
    out[((size_t)(b*3 + 2) << 16) + pix] = r2;
}

extern "C" void kernel_launch(void* const* d_in, const int* in_sizes, int n_in,
                              void* d_out, int out_size, void* d_ws, size_t ws_size,
                              hipStream_t stream)
{
    const float* feat = (const float*)d_in[0];
    const float* w1m  = (const float*)d_in[1];
    const float* b1m  = (const float*)d_in[2];
    const float* w2m  = (const float*)d_in[3];
    const float* b2m  = (const float*)d_in[4];
    const float* wk1  = (const float*)d_in[5];
    const float* bk1  = (const float*)d_in[6];
    const float* wk2  = (const float*)d_in[7];
    const float* bk2  = (const float*)d_in[8];
    const float* wr1  = (const float*)d_in[9];
    const float* br1  = (const float*)d_in[10];
    const float* wr2  = (const float*)d_in[11];
    const float* br2  = (const float*)d_in[12];

    float* out     = (float*)d_out;
    float* contrib = (float*)d_ws;   // 4*128 floats

    hipLaunchKernelGGL(prep_kernel, dim3(1), dim3(256), 0, stream,
                       w1m, b1m, w2m, b2m, wk1, bk1, contrib);
    hipLaunchKernelGGL(main_kernel, dim3(512), dim3(256), 0, stream,
                       feat, wk1, wk2, bk2, wr1, br1, wr2, br2, contrib, out);
}

// Round 2
// 406.244 us; speedup vs baseline: 3.1149x; 3.1149x over previous
//
#include <hip/hip_runtime.h>
#include <math.h>

#define HH 128
#define WW 128
#define CC 64

typedef __attribute__((ext_vector_type(8))) short s16x8;
typedef __attribute__((ext_vector_type(4))) float f32x4;

__device__ __forceinline__ float gelu_f(float x){
    return 0.5f * x * (1.0f + erff(x * 0.70710678118654752440f));
}
__device__ __forceinline__ int refl(int v, int n){
    return v < 0 ? -v : (v >= n ? 2*n - 2 - v : v);
}
__device__ __forceinline__ ushort f2bf(float f){
    unsigned int b = __float_as_uint(f);
    unsigned int r = (b + 0x7FFFu + ((b >> 16) & 1u)) >> 16;
    return (ushort)r;
}

// ---------------------------------------------------------------------------
// prep_kernel: contrib[p][o] = bk1[o] + wk1[o,576:640] . m_emb[p]   (4 x 128)
// ---------------------------------------------------------------------------
__global__ __launch_bounds__(256) void prep_kernel(
    const float* __restrict__ w1m, const float* __restrict__ b1m,
    const float* __restrict__ w2m, const float* __restrict__ b2m,
    const float* __restrict__ wk1, const float* __restrict__ bk1,
    float* __restrict__ contrib)
{
    __shared__ float m_emb[4][64];
    const int t = threadIdx.x;
    const int p = t >> 6;
    const int o = t & 63;

    const float du = (p & 1) ? -0.25f : 0.25f;
    const float dv = (p >> 1) ? -0.25f : 0.25f;
    const float mv[5] = {2.0f, du, dv, 0.5f, 0.3f};

    float enc[85];
    #pragma unroll
    for (int f = 0; f < 5; ++f){
        enc[f*17] = mv[f];
        float fr = 3.14159265358979323846f;
        #pragma unroll
        for (int b = 0; b < 8; ++b){
            float xb = mv[f] * fr;
            enc[f*17 + 1 + b] = sinf(xb);
            enc[f*17 + 9 + b] = cosf(xb);
            fr *= 2.0f;
        }
    }

    float acc = b2m[o];
    for (int j = 0; j < 64; ++j){
        float h = b1m[j];
        #pragma unroll
        for (int i = 0; i < 85; ++i) h += enc[i] * w1m[j*85 + i];
        acc += gelu_f(h) * w2m[o*64 + j];
    }
    m_emb[p][o] = acc;
    __syncthreads();

    for (int e = t; e < 512; e += 256){
        const int pp = e >> 7;
        const int oo = e & 127;
        float a = bk1[oo];
        #pragma unroll
        for (int j = 0; j < 64; ++j) a += m_emb[pp][j] * wk1[oo*640 + 576 + j];
        contrib[e] = a;
    }
}

// ---------------------------------------------------------------------------
// prep_w: wk1hat[o][c*12+kk] = bf16(wk1[o][c*9+kk]) (kk<9) else 0.  128x768
// ---------------------------------------------------------------------------
__global__ __launch_bounds__(256) void prep_w(
    const float* __restrict__ wk1, ushort* __restrict__ wk1hat)
{
    for (int i = blockIdx.x*256 + threadIdx.x; i < 128*768; i += 96*256){
        const int o = i / 768, khat = i % 768;
        const int c = khat / 12, kk = khat % 12;
        const float v = (kk < 9) ? wk1[o*640 + c*9 + kk] : 0.0f;
        wk1hat[i] = f2bf(v);
    }
}

// ---------------------------------------------------------------------------
// conv_kernel: L[b][cell][o] = sum_k patch[cell][k] * wk1[o][k]  (pre-bias)
// bf16 MFMA 16x16x32. Block: 64 cells (2 rows x 32 cx) x 128 outs, 4 waves.
// ---------------------------------------------------------------------------
__global__ __launch_bounds__(256) void conv_kernel(
    const float* __restrict__ feat,
    const ushort* __restrict__ wk1hat,
    float* __restrict__ L)
{
    __shared__ ushort As[64][104];   // [cell][khat-in-chunk], padded 96->104
    __shared__ ushort Bs[128][104];  // [out][khat-in-chunk]

    const int t   = threadIdx.x;
    const int blk = blockIdx.x;
    const int b   = blk >> 8;
    const int rem = blk & 255;
    const int cy0 = (rem >> 2) * 2;
    const int cx0 = (rem & 3) * 32;

    const int lane = t & 63;
    const int w    = t >> 6;
    const int wm   = w >> 1;        // cell half (0/1 -> 32 cells each)
    const int wn   = w & 1;         // out half  (0/1 -> 64 outs each)
    const int l15  = lane & 15;
    const int l4   = lane >> 4;

    int rowIdx[4];
    #pragma unroll
    for (int rr = 0; rr < 4; ++rr) rowIdx[rr] = refl(cy0 - 1 + rr, HH);

    const float* __restrict__ fb = feat + (size_t)b * CC * HH * WW;

    f32x4 acc[2][4];
    #pragma unroll
    for (int m = 0; m < 2; ++m)
        #pragma unroll
        for (int n = 0; n < 4; ++n) acc[m][n] = (f32x4){0.f,0.f,0.f,0.f};

    for (int cc = 0; cc < 8; ++cc){
        const int cbase = cc * 8;

        // ---- stage A (im2col, bf16). khat uniform per wave -> coalesced ----
        for (int e = t; e < 6144; e += 256){
            const int khat = e >> 6;          // 0..95 (uniform per wave)
            const int cell = e & 63;
            const int c  = khat / 12;
            const int kk = khat % 12;
            float v = 0.0f;
            if (kk < 9){
                const int ky = kk / 3;
                const int kx = kk - ky * 3;
                const int r = cell >> 5, x = cell & 31;
                const int row = rowIdx[r + ky];
                const int col = refl(cx0 + x + kx - 1, WW);
                v = fb[(size_t)(cbase + c) * (HH*WW) + row * WW + col];
            }
            As[cell][khat] = f2bf(v);
        }

        // ---- stage B from wk1hat (bf16, coalesced 16B copies) ----
        {
            const int o = t >> 1, half = t & 1;
            const ushort* src = wk1hat + o * 768 + cc * 96 + half * 48;
            ushort* dst = &Bs[o][half * 48];
            #pragma unroll
            for (int i = 0; i < 6; ++i)
                ((int4*)dst)[i] = ((const int4*)src)[i];
        }
        __syncthreads();

        // ---- 3 MFMA K-steps of 32 ----
        #pragma unroll
        for (int ks = 0; ks < 3; ++ks){
            const int kb = ks * 32 + l4 * 8;
            const s16x8 a0 = *(const s16x8*)&As[wm*32 + l15][kb];
            const s16x8 a1 = *(const s16x8*)&As[wm*32 + 16 + l15][kb];
            #pragma unroll
            for (int n = 0; n < 4; ++n){
                const s16x8 bf = *(const s16x8*)&Bs[wn*64 + n*16 + l15][kb];
                acc[0][n] = __builtin_amdgcn_mfma_f32_16x16x32_bf16(a0, bf, acc[0][n], 0, 0, 0);
                acc[1][n] = __builtin_amdgcn_mfma_f32_16x16x32_bf16(a1, bf, acc[1][n], 0, 0, 0);
            }
        }
        __syncthreads();
    }

    // ---- epilogue: D row=cell (row=(l>>4)*4+reg), col=out (l&15) ----
    #pragma unroll
    for (int m = 0; m < 2; ++m){
        #pragma unroll
        for (int n = 0; n < 4; ++n){
            #pragma unroll
            for (int reg = 0; reg < 4; ++reg){
                const int cl = wm*32 + m*16 + l4*4 + reg;
                const int o  = wn*64 + n*16 + l15;
                const int cellg = (cy0 + (cl >> 5)) * WW + cx0 + (cl & 31);
                L[(((size_t)b * (HH*WW) + cellg) << 7) + o] = acc[m][n][reg];
            }
        }
    }
}

// ---------------------------------------------------------------------------
// pixel_kernel: per-pixel tail. 1 thread = 1 output pixel.
// ---------------------------------------------------------------------------
__global__ __launch_bounds__(256) void pixel_kernel(
    const float* __restrict__ feat,
    const float* __restrict__ L,
    const float* __restrict__ contrib,
    const float* __restrict__ wk2, const float* __restrict__ bk2,
    const float* __restrict__ wr1, const float* __restrict__ br1,
    const float* __restrict__ wr2, const float* __restrict__ br2,
    float* __restrict__ out)
{
    __shared__ float cl_s[512];
    for (int e = threadIdx.x; e < 512; e += 256) cl_s[e] = contrib[e];
    __syncthreads();

    const int tid = blockIdx.x * 256 + threadIdx.x;
    const int b  = tid >> 16;
    const int qi = tid & 65535;
    const int oy = qi >> 8;
    const int ox = qi & 255;

    int cy = (oy - 1) >> 1; if (cy < 0) cy = 0;
    int cx = (ox - 1) >> 1; if (cx < 0) cx = 0;

    int ry[3], rx[3];
    #pragma unroll
    for (int k = 0; k < 3; ++k){
        ry[k] = refl(cy - 1 + k, HH);
        rx[k] = refl(cx - 1 + k, WW);
    }

    const int p = ((oy & 1) << 1) | (ox & 1);
    const float* __restrict__ fb = feat + (size_t)b * CC * HH * WW;
    const f32x4* __restrict__ Lp =
        (const f32x4*)(L + (((size_t)b * (HH*WW) + cy * WW + cx) << 7));

    // ---- logits -> gelu -> w9 ----
    float w9[9];
    #pragma unroll
    for (int k = 0; k < 9; ++k) w9[k] = bk2[k];

    for (int oo = 0; oo < 32; ++oo){
        const f32x4 lv = Lp[oo];
        #pragma unroll
        for (int j = 0; j < 4; ++j){
            const int o = oo*4 + j;
            const float h = gelu_f(lv[j] + cl_s[p*128 + o]);
            #pragma unroll
            for (int k = 0; k < 9; ++k) w9[k] += h * wk2[k*128 + o];
        }
    }

    // ---- softmax over 9 ----
    float mx = w9[0];
    #pragma unroll
    for (int k = 1; k < 9; ++k) mx = fmaxf(mx, w9[k]);
    float sum = 0.0f;
    #pragma unroll
    for (int k = 0; k < 9; ++k){ w9[k] = expf(w9[k] - mx); sum += w9[k]; }
    const float inv = 1.0f / sum;
    #pragma unroll
    for (int k = 0; k < 9; ++k) w9[k] *= inv;

    // ---- f_q (the (K2,C)-reinterpret mix), exact fp32 gather ----
    float fq[64];
    #pragma unroll
    for (int c = 0; c < 64; ++c){
        float a = 0.0f;
        #pragma unroll
        for (int k = 0; k < 9; ++k){
            const int j  = k*64 + c;
            const int ch = j / 9;      // compile-time after unroll
            const int kk = j % 9;
            a += w9[k] * fb[ch*(HH*WW) + ry[kk/3]*WW + rx[kk%3]];
        }
        fq[c] = a;
    }

    // ---- RGB MLP ----
    float r0 = br2[0], r1 = br2[1], r2 = br2[2];
    for (int o = 0; o < 64; ++o){
        float a = br1[o];
        #pragma unroll
        for (int c = 0; c < 64; ++c) a += fq[c] * wr1[o*64 + c];
        const float h = gelu_f(a);
        r0 += h * wr2[o];
        r1 += h * wr2[64 + o];
        r2 += h * wr2[128 + o];
    }

    const int pix = (oy << 8) | ox;
    out[((size_t)(b*3 + 0) << 16) + pix] = r0;
    out[((size_t)(b*3 + 1) << 16) + pix] = r1;
    out[((size_t)(b*3 + 2) << 16) + pix] = r2;
}

// ---------------------------------------------------------------------------
// Fallback monolithic kernel (round-1, used only if ws too small)
// ---------------------------------------------------------------------------
__global__ __launch_bounds__(256) void main_kernel_mono(
    const float* __restrict__ feat,
    const float* __restrict__ wk1,
    const float* __restrict__ wk2, const float* __restrict__ bk2,
    const float* __restrict__ wr1, const float* __restrict__ br1,
    const float* __restrict__ wr2, const float* __restrict__ br2,
    const float* __restrict__ contrib,
    float* __restrict__ out)
{
    const int tid = blockIdx.x * 256 + threadIdx.x;
    const int b  = tid >> 16;
    const int qi = tid & 65535;
    const int oy = qi >> 8;
    const int ox = qi & 255;

    int cy = (oy - 1) >> 1; if (cy < 0) cy = 0;
    int cx = (ox - 1) >> 1; if (cx < 0) cx = 0;

    int ry[3], rx[3];
    #pragma unroll
    for (int k = 0; k < 3; ++k){ ry[k] = refl(cy-1+k, HH); rx[k] = refl(cx-1+k, WW); }

    const int p = ((oy & 1) << 1) | (ox & 1);
    const float* __restrict__ fb = feat + (size_t)b * CC * HH * WW;

    float w9[9];
    #pragma unroll
    for (int k = 0; k < 9; ++k) w9[k] = bk2[k];

    for (int oc = 0; oc < 4; ++oc){
        float acc[32];
        #pragma unroll
        for (int j = 0; j < 32; ++j) acc[j] = contrib[p*128 + oc*32 + j];
        for (int c = 0; c < CC; ++c){
            const float* __restrict__ fc = fb + c * (HH*WW);
            float v[9];
            #pragma unroll
            for (int ky = 0; ky < 3; ++ky){
                const float* __restrict__ frow = fc + ry[ky] * WW;
                #pragma unroll
                for (int kx = 0; kx < 3; ++kx) v[ky*3 + kx] = frow[rx[kx]];
            }
            const float* __restrict__ wrow0 = wk1 + (oc*32) * 640 + c * 9;
            #pragma unroll
            for (int j = 0; j < 32; ++j){
                const float* __restrict__ wrow = wrow0 + j * 640;
                float a = acc[j];
                #pragma unroll
                for (int kk = 0; kk < 9; ++kk) a += v[kk] * wrow[kk];
                acc[j] = a;
            }
        }
        #pragma unroll
        for (int j = 0; j < 32; ++j){
            const float h = gelu_f(acc[j]);
            const int o = oc*32 + j;
            #pragma unroll
            for (int k = 0; k < 9; ++k) w9[k] += h * wk2[k*128 + o];
        }
    }

    float mx = w9[0];
    #pragma unroll
    for (int k = 1; k < 9; ++k) mx = fmaxf(mx, w9[k]);
    float sum = 0.0f;
    #pragma unroll
    for (int k = 0; k < 9; ++k){ w9[k] = expf(w9[k] - mx); sum += w9[k]; }
    const float inv = 1.0f / sum;
    #pragma unroll
    for (int k = 0; k < 9; ++k) w9[k] *= inv;

    float fq[64];
    #pragma unroll
    for (int c = 0; c < 64; ++c){
        float a = 0.0f;
        #pragma unroll
        for (int k = 0; k < 9; ++k){
            const int j  = k*64 + c;
            const int ch = j / 9;
            const int kk = j % 9;
            a += w9[k] * fb[ch*(HH*WW) + ry[kk/3]*WW + rx[kk%3]];
        }
        fq[c] = a;
    }

    float r0 = br2[0], r1 = br2[1], r2 = br2[2];
    for (int o = 0; o < 64; ++o){
        float a = br1[o];
        #pragma unroll
        for (int c = 0; c < 64; ++c) a += fq[c] * wr1[o*64 + c];
        const float h = gelu_f(a);
        r0 += h * wr2[o];
        r1 += h * wr2[64 + o];
        r2 += h * wr2[128 + o];
    }

    const int pix = (oy << 8) | ox;
    out[((size_t)(b*3 + 0) << 16) + pix] = r0;
    out[((size_t)(b*3 + 1) << 16) + pix] = r1;
    out[((size_t)(b*3 + 2) << 16) + pix] = r2;
}

extern "C" void kernel_launch(void* const* d_in, const int* in_sizes, int n_in,
                              void* d_out, int out_size, void* d_ws, size_t ws_size,
                              hipStream_t stream)
{
    const float* feat = (const float*)d_in[0];
    const float* w1m  = (const float*)d_in[1];
    const float* b1m  = (const float*)d_in[2];
    const float* w2m  = (const float*)d_in[3];
    const float* b2m  = (const float*)d_in[4];
    const float* wk1  = (const float*)d_in[5];
    const float* bk1  = (const float*)d_in[6];
    const float* wk2  = (const float*)d_in[7];
    const float* bk2  = (const float*)d_in[8];
    const float* wr1  = (const float*)d_in[9];
    const float* br1  = (const float*)d_in[10];
    const float* wr2  = (const float*)d_in[11];
    const float* br2  = (const float*)d_in[12];

    float* out = (float*)d_out;

    // ws layout: [contrib 2048B][wk1hat 196608B][L 16777216B]
    float*  contrib = (float*)d_ws;
    ushort* wk1hat  = (ushort*)((char*)d_ws + 2048);
    float*  L       = (float*)((char*)d_ws + 2048 + 196608);
    const size_t need = 2048 + 196608 + (size_t)2*128*128*128*sizeof(float);

    hipLaunchKernelGGL(prep_kernel, dim3(1), dim3(256), 0, stream,
                       w1m, b1m, w2m, b2m, wk1, bk1, contrib);

    if (ws_size >= need){
        hipLaunchKernelGGL(prep_w, dim3(96), dim3(256), 0, stream, wk1, wk1hat);
        hipLaunchKernelGGL(conv_kernel, dim3(512), dim3(256), 0, stream,
                           feat, wk1hat, L);
        hipLaunchKernelGGL(pixel_kernel, dim3(512), dim3(256), 0, stream,
                           feat, L, contrib, wk2, bk2, wr1, br1, wr2, br2, out);
    } else {
        hipLaunchKernelGGL(main_kernel_mono, dim3(512), dim3(256), 0, stream,
                           feat, wk1, wk2, bk2, wr1, br1, wr2, br2, contrib, out);
    }
}